// Round 1
// 301.885 us; speedup vs baseline: 1.1166x; 1.1166x over previous
//
#include <hip/hip_runtime.h>
#include <stdint.h>

#define NL 64    // labels
#define NCOL 32  // privatization columns (col = tid & 31; 2-way bank alias = free)

typedef float f32x4 __attribute__((ext_vector_type(4)));

// No-return LDS f64 atomic add (ds_add_f64, gfx90a+/gfx950).
// Low 32 bits of the flat-cast LDS pointer are the DS byte offset.
static __device__ __forceinline__ void lds_add_f64(double* p, double v) {
    asm volatile("ds_add_f64 %0, %1"
                 :
                 : "v"((uint32_t)(uintptr_t)p), "v"(v)
                 : "memory");
}

// Phase 1: packed-bin reduce. Bin value = count*2^32 + sum (one ds_add_f64 per
// element instead of ds_add_f32 + ds_add_u32). Per-block per-bin count <= ~400
// -> magnitude <= 2^41, ulp 2^-11: mean error ~1e-7, far under tolerance.
// 2-ahead register pipeline keeps 4-6 global loads in flight per wave.
// LDS 18.4 KB -> 8 blocks/CU; launch_bounds(256,8) -> 32 waves/CU.
__global__ __launch_bounds__(256, 8) void tl_reduce(const float* __restrict__ tex,
                                                    const int* __restrict__ lab,
                                                    float* __restrict__ g_sums,
                                                    unsigned int* __restrict__ g_cnts,
                                                    int n) {
    __shared__ double s_bin[NL * NCOL];  // 16 KB
    __shared__ float s_s[256];           // 1 KB
    __shared__ unsigned s_c[256];        // 1 KB

    const int tid = threadIdx.x;
    const int col = tid & (NCOL - 1);

    for (int k = tid; k < NL * NCOL; k += 256) s_bin[k] = 0.0;
    __syncthreads();

    const int n4 = n >> 2;
    const float4* __restrict__ tex4 = (const float4*)tex;
    const int4* __restrict__ lab4 = (const int4*)lab;
    const int stride = gridDim.x * 256;

    int i = blockIdx.x * 256 + tid;
    bool vA = i < n4;
    bool vB = (i + stride) < n4;
    float4 tA, tB;
    int4 lA, lB;
    if (vA) { tA = tex4[i]; lA = lab4[i]; }
    if (vB) { tB = tex4[i + stride]; lB = lab4[i + stride]; }

    while (vA) {
        const int iC = i + 2 * stride;
        const bool vC = iC < n4;
        float4 tC;
        int4 lC;
        if (vC) { tC = tex4[iC]; lC = lab4[iC]; }

        lds_add_f64(&s_bin[((lA.x & (NL - 1)) << 5) | col], (double)tA.x + 4294967296.0);
        lds_add_f64(&s_bin[((lA.y & (NL - 1)) << 5) | col], (double)tA.y + 4294967296.0);
        lds_add_f64(&s_bin[((lA.z & (NL - 1)) << 5) | col], (double)tA.z + 4294967296.0);
        lds_add_f64(&s_bin[((lA.w & (NL - 1)) << 5) | col], (double)tA.w + 4294967296.0);

        tA = tB; lA = lB; vA = vB;
        tB = tC; lB = lC; vB = vC;
        i += stride;
    }

    // scalar tail (n % 4), block 0 only
    if (blockIdx.x == 0) {
        const int base = n4 << 2;
        if (tid < n - base) {
            const int j = base + tid;
            lds_add_f64(&s_bin[((lab[j] & (NL - 1)) << 5) | col], (double)tex[j] + 4294967296.0);
        }
    }
    __syncthreads();

    // Extract: thread t -> label t>>2, quarter t&3 (8 cols). Sum raw f64 then
    // split once: count = round(v * 2^-32), sum = v - count*2^32 (exact).
    {
        const int l = tid >> 2, q = tid & 3;
        double v = 0.0;
#pragma unroll
        for (int j = 0; j < 8; ++j) v += s_bin[(l << 5) | (q << 3) | j];
        const double ci = floor(v * (1.0 / 4294967296.0) + 0.5);
        s_s[tid] = (float)(v - ci * 4294967296.0);
        s_c[tid] = (unsigned)ci;
    }
    __syncthreads();

    if (tid < NL) {
        const int b = tid << 2;
        atomicAdd(&g_sums[tid], s_s[b] + s_s[b + 1] + s_s[b + 2] + s_s[b + 3]);
        atomicAdd(&g_cnts[tid], s_c[b] + s_c[b + 1] + s_c[b + 2] + s_c[b + 3]);
    }
}

// Phase 2: delta table in LDS, out = tex - delta[lab]. Same 2-ahead pipeline;
// nontemporal stores for the write-only output stream (tex/lab stay cacheable,
// they are L3-warm from phase 1).
__global__ __launch_bounds__(256, 8) void tl_apply(const float* __restrict__ tex,
                                                   const int* __restrict__ lab,
                                                   const float* __restrict__ g_sums,
                                                   const unsigned int* __restrict__ g_cnts,
                                                   const float* __restrict__ intens,
                                                   float* __restrict__ out, int n) {
    __shared__ float s_delta[NL];
    if (threadIdx.x < NL) {
        const int l = threadIdx.x;
        const float mean = g_sums[l] / fmaxf((float)g_cnts[l], 1.0f);
        s_delta[l] = (l > 0) ? (mean - intens[l]) : 0.0f;
    }
    __syncthreads();

    const int tid = threadIdx.x;
    const int n4 = n >> 2;
    const float4* __restrict__ tex4 = (const float4*)tex;
    const int4* __restrict__ lab4 = (const int4*)lab;
    float4* __restrict__ out4 = (float4*)out;
    const int stride = gridDim.x * 256;

    int i = blockIdx.x * 256 + tid;
    bool vA = i < n4;
    bool vB = (i + stride) < n4;
    float4 tA, tB;
    int4 lA, lB;
    if (vA) { tA = tex4[i]; lA = lab4[i]; }
    if (vB) { tB = tex4[i + stride]; lB = lab4[i + stride]; }

    while (vA) {
        const int iC = i + 2 * stride;
        const bool vC = iC < n4;
        float4 tC;
        int4 lC;
        if (vC) { tC = tex4[iC]; lC = lab4[iC]; }

        float4 o;
        o.x = tA.x - s_delta[lA.x & (NL - 1)];
        o.y = tA.y - s_delta[lA.y & (NL - 1)];
        o.z = tA.z - s_delta[lA.z & (NL - 1)];
        o.w = tA.w - s_delta[lA.w & (NL - 1)];
        __builtin_nontemporal_store(*(const f32x4*)&o, (f32x4*)&out4[i]);

        tA = tB; lA = lB; vA = vB;
        tB = tC; lB = lC; vB = vC;
        i += stride;
    }

    if (blockIdx.x == 0) {
        const int base = n4 << 2;
        if (tid < n - base) {
            const int j = base + tid;
            out[j] = tex[j] - s_delta[lab[j] & (NL - 1)];
        }
    }
}

extern "C" void kernel_launch(void* const* d_in, const int* in_sizes, int n_in,
                              void* d_out, int out_size, void* d_ws, size_t ws_size,
                              hipStream_t stream) {
    const float* tex    = (const float*)d_in[0];
    const int*   lab    = (const int*)d_in[1];
    const float* intens = (const float*)d_in[2];
    float* out = (float*)d_out;
    const int n = in_sizes[0];

    float* g_sums = (float*)d_ws;
    unsigned int* g_cnts = (unsigned int*)((char*)d_ws + NL * sizeof(float));

    // d_ws is re-poisoned before every timed launch — zero the 512 B of bins.
    hipMemsetAsync(d_ws, 0, NL * (sizeof(float) + sizeof(unsigned int)), stream);

    // Phase 1: 2048 blocks = 8 blocks/CU x 256 CUs, fully co-resident.
    tl_reduce<<<2048, 256, 0, stream>>>(tex, lab, g_sums, g_cnts, n);

    // Phase 2: grid-stride, 4096 blocks (6 float4 per thread at n=25.1M).
    tl_apply<<<4096, 256, 0, stream>>>(tex, lab, g_sums, g_cnts, intens, out, n);
}